// Round 5
// baseline (164.211 us; speedup 1.0000x reference)
//
#include <hip/hip_runtime.h>

#define INF __builtin_inff()

typedef __attribute__((ext_vector_type(8))) short bf16x8;
typedef __attribute__((ext_vector_type(4))) short s16x4;
typedef __attribute__((ext_vector_type(4))) float f32x4;
typedef __attribute__((ext_vector_type(8))) unsigned short u16x8;
typedef __attribute__((ext_vector_type(4))) unsigned short u16x4;

#define MFMA16(a, b, c) __builtin_amdgcn_mfma_f32_16x16x32_bf16(a, b, c, 0, 0, 0)

// async global->LDS, 16B per lane; LDS dest = wave-uniform base + lane*16
#define ASYNC16(g, l) __builtin_amdgcn_global_load_lds( \
    (const __attribute__((address_space(1))) unsigned int*)(const void*)(g), \
    (__attribute__((address_space(3))) unsigned int*)(void*)(l), 16, 0, 0)

#if __has_builtin(__builtin_amdgcn_exp2f)
#define EXP2(x) __builtin_amdgcn_exp2f(x)
#else
#define EXP2(x) exp2f(x)
#endif

// 0.125 (dh^-0.5) * log2(e): folded into Q so attention runs in exp2 domain
#define QSCALE 0.18033688011112042f

__device__ __forceinline__ unsigned short f2bf(float f) {
  union { float f; unsigned u; } v; v.f = f;
  unsigned r = v.u + 0x7fffu + ((v.u >> 16) & 1u);   // RNE
  return (unsigned short)(r >> 16);
}

// == PREP: scan (4) | weight transposes (4096) | x gather-cvt (1024) | masked-row bias fill (256) ==
__global__ __launch_bounds__(256) void k_prep(
    const float* __restrict__ x, const float* __restrict__ mask,
    const float* __restrict__ wqkv, const float* __restrict__ wout,
    unsigned short* __restrict__ xc, unsigned short* __restrict__ wqkvt,
    unsigned short* __restrict__ woutt, unsigned short* __restrict__ perm,
    int* __restrict__ nvb, const float* __restrict__ bias, float* __restrict__ C) {
  __shared__ union {
    float tile[32][33];
    struct { unsigned short lperm[1024]; int wtot[4]; } sc;
  } sh;
  const int lid = blockIdx.x;
  const int t = threadIdx.x, lane = t & 63, wid = t >> 6;

  if (lid >= 5124) {
    // ---- masked-row bias fill: token masked <=> mask==0; these rows are bias-only
    const int idx = lid - 5124;
    const int b = idx >> 6, g = idx & 63;
    const float4 bv = ((const float4*)bias)[t];
    const float* mrow = mask + b * 1024 + g * 16;
#pragma unroll
    for (int j = 0; j < 16; ++j) {
      if (mrow[j] == 0.f)
        ((float4*)(C + ((size_t)(b * 1024 + g * 16 + j)) * 1024))[t] = bv;
    }
    return;
  }

  if (lid >= 4 && lid < 4100) {
    // ---- weight transpose fp32 [R][C] -> bf16 [C][R]
    int id = lid - 4;
    const float* src; unsigned short* dst; int Cc, bc, br;
    if (id < 3072) { src = wqkv; dst = wqkvt; Cc = 3072; bc = (id % 96) * 32; br = (id / 96) * 32; }
    else { id -= 3072; src = wout; dst = woutt; Cc = 1024; bc = (id & 31) * 32; br = (id >> 5) * 32; }
    const int tx = t & 31, ty = t >> 5;
#pragma unroll
    for (int i = 0; i < 32; i += 8)
      sh.tile[ty + i][tx] = src[(size_t)(br + ty + i) * Cc + bc + tx];
    __syncthreads();
#pragma unroll
    for (int i = 0; i < 32; i += 8)
      dst[(size_t)(bc + ty + i) * 1024 + br + tx] = f2bf(sh.tile[tx][ty + i]);
    return;
  }

  // ---- per-batch mask scan (both remaining roles need it)
  const int b = (lid < 4) ? lid : ((lid - 4100) >> 8);
  float4 mv = ((const float4*)(mask + b * 1024))[t];
  int v0 = mv.x != 0.f, v1 = mv.y != 0.f, v2 = mv.z != 0.f, v3 = mv.w != 0.f;
  int cnt = v0 + v1 + v2 + v3;
  int pre = cnt;
#pragma unroll
  for (int d = 1; d < 64; d <<= 1) { int n = __shfl_up(pre, d); if (lane >= d) pre += n; }
  if (lane == 63) sh.sc.wtot[wid] = pre;
  __syncthreads();
  int base = 0;
#pragma unroll
  for (int i = 0; i < 4; ++i) if (i < wid) base += sh.sc.wtot[i];
  const int nvt = sh.sc.wtot[0] + sh.sc.wtot[1] + sh.sc.wtot[2] + sh.sc.wtot[3];
  int ex = base + pre - cnt;                      // # valid before token 4t
  int vv[4] = { v0, v1, v2, v3 };

  if (lid < 4) {
    // ---- scan writeback: perm[0..nv)=valid, [nv..1024)=masked
#pragma unroll
    for (int j = 0; j < 4; ++j) {
      int tok = t * 4 + j;
      if (vv[j]) { perm[b * 1024 + ex] = (unsigned short)tok; ++ex; }
      else         perm[b * 1024 + nvt + (tok - ex)] = (unsigned short)tok;
    }
    if (t == 0) nvb[b] = nvt;
    return;
  }

  // ---- gather-convert 4 x-rows into compacted xc (zero-pad to ceil128)
#pragma unroll
  for (int j = 0; j < 4; ++j) {
    int tok = t * 4 + j;
    if (vv[j]) { sh.sc.lperm[ex] = (unsigned short)tok; ++ex; }
  }
  __syncthreads();
  const int s0 = ((lid - 4100) & 255) * 4;
  const int ce = (nvt + 127) & ~127;
#pragma unroll
  for (int j = 0; j < 4; ++j) {
    int slot = s0 + j;
    if (slot >= ce) continue;
    u16x4 o;
    if (slot < nvt) {
      int tok = sh.sc.lperm[slot];
      float4 f = ((const float4*)(x + ((size_t)(b * 1024 + tok)) * 1024))[t];
      o[0] = f2bf(f.x); o[1] = f2bf(f.y); o[2] = f2bf(f.z); o[3] = f2bf(f.w);
    } else {
      o[0] = o[1] = o[2] = o[3] = 0;
    }
    ((u16x4*)(xc + ((size_t)(b * 1024 + slot)) * 1024))[t] = o;
  }
}

// ---------- GEMM1 (double-buffered): qkv = xc @ w_qkv -> qcmp/kcmp + V^T fused ----------
__global__ __launch_bounds__(256) void k_gemm_qkv(
    const unsigned short* __restrict__ A, const unsigned short* __restrict__ Bt,
    const int* __restrict__ nvb,
    unsigned short* __restrict__ qcmp, unsigned short* __restrict__ kcmp,
    unsigned short* __restrict__ vt) {
  __shared__ unsigned short SH[32768];        // 64 KB: 2 x (As[128][64] | Bs[128][64])
  const int lid = blockIdx.x;
  const int xcd = lid & 7, i6 = lid >> 3;
  const int colt = xcd * 3 + (i6 % 3);
  const int rowt = i6 / 3;
  const int b = rowt >> 3, mt = rowt & 7;
  const int nv = nvb[b];
  if (mt * 128 >= nv) return;
  const int bm0 = mt * 128;
  const int bn0 = colt * 128;
  const size_t abase = ((size_t)(b * 1024 + bm0)) * 1024;
  const int t = threadIdx.x;
  const int lane = t & 63, wave = t >> 6;
  const int wm = (wave >> 1) * 64, wn = (wave & 1) * 64;
  const int lr = lane & 15, quad = lane >> 4;
  const int sw = lr & 7;
  f32x4 acc[4][4] = {};
  auto stage = [&](int pp, int k0) {
    unsigned short* As = SH + pp * 16384;
    unsigned short* Bs = As + 8192;
#pragma unroll
    for (int j = 0; j < 4; ++j) {
      int idx = t + j * 256;
      int row = idx >> 3;
      int g = (idx ^ row) & 7;                // chunk XOR swizzle
      ASYNC16(&A[abase + (size_t)row * 1024 + k0 + g * 8], &As[idx * 8]);
      ASYNC16(&Bt[((size_t)(bn0 + row)) * 1024 + k0 + g * 8], &Bs[idx * 8]);
    }
  };
  stage(0, 0);
  for (int it = 0; it < 16; ++it) {
    const int pp = it & 1;
    __syncthreads();
    if (it + 1 < 16) stage(1 - pp, (it + 1) * 64);
    const unsigned short* As = SH + pp * 16384;
    const unsigned short* Bs = As + 8192;
#pragma unroll
    for (int ks = 0; ks < 2; ++ks) {
      bf16x8 af[4], bfr[4];
#pragma unroll
      for (int i = 0; i < 4; ++i)
        af[i] = *(const bf16x8*)(&As[(wm + i * 16 + lr) * 64 + (((ks * 4 + quad) ^ sw)) * 8]);
#pragma unroll
      for (int j = 0; j < 4; ++j)
        bfr[j] = *(const bf16x8*)(&Bs[(wn + j * 16 + lr) * 64 + (((ks * 4 + quad) ^ sw)) * 8]);
#pragma unroll
      for (int i = 0; i < 4; ++i)
#pragma unroll
        for (int j = 0; j < 4; ++j)
          acc[i][j] = MFMA16(af[i], bfr[j], acc[i][j]);
    }
  }
  // epilogue: repack 64-row halves into SH[64][136]; Q/K row stores, V transposed stores
  const int sec = bn0 >> 10;
  const int js0 = bn0 & 1023;
  const float qs = (sec == 0) ? QSCALE : 1.f;   // fold softmax scale+log2e into Q
#pragma unroll
  for (int hh = 0; hh < 2; ++hh) {
    __syncthreads();
    if ((wave >> 1) == hh) {
#pragma unroll
      for (int i = 0; i < 4; ++i)
#pragma unroll
        for (int j = 0; j < 4; ++j)
#pragma unroll
          for (int r = 0; r < 4; ++r)
            SH[(i * 16 + quad * 4 + r) * 136 + wn + j * 16 + lr] = f2bf(acc[i][j][r] * qs);
    }
    __syncthreads();
    if (sec < 2) {
      unsigned short* dstT = sec ? kcmp : qcmp;
#pragma unroll
      for (int rr = 0; rr < 4; ++rr) {
        int lrow = (t >> 4) + rr * 16;
        int ck = t & 15;
        int slot = bm0 + hh * 64 + lrow;
        int js = js0 + ck * 8;
        int h = js >> 6, d = js & 63;
        u16x8 v = *(u16x8*)(&SH[lrow * 136 + ck * 8]);
        *(u16x8*)(&dstT[(((size_t)(b * 16 + h)) * 1024 + slot) * 64 + d]) = v;
      }
    } else {
      const int c = t & 127, seg = t >> 7;
      const int js = js0 + c, h = js >> 6, d = js & 63;
      unsigned short* vrow =
          &vt[(((size_t)(b * 16 + h)) * 64 + d) * 1024 + bm0 + hh * 64 + seg * 32];
#pragma unroll
      for (int s4 = 0; s4 < 4; ++s4) {
        u16x8 v;
#pragma unroll
        for (int s = 0; s < 8; ++s) v[s] = SH[(seg * 32 + s4 * 8 + s) * 136 + c];
        *(u16x8*)(vrow + s4 * 8) = v;
      }
    }
  }
}

// ---------- Flash attention: K staged in LDS (double-buffered); V read direct from L2 ----------
// V working set is XCD-affine and L2-resident (~1 MB/XCD) -> staging it in LDS is pure
// overhead (Common-mistake #7). V frags issued EARLY (before softmax) so the softmax
// VALU chain hides the L2 latency. Q pre-scaled by 0.125*log2e; defer-max (THR=8).
__global__ __launch_bounds__(256, 3) void k_attn(
    const unsigned short* __restrict__ qcmp, const unsigned short* __restrict__ kcmp,
    const unsigned short* __restrict__ vtc, const int* __restrict__ nvb,
    unsigned short* __restrict__ aoc) {
  __shared__ unsigned short Ks[2][4096];
  __shared__ unsigned short P[4][16 * 72];
  const int bx = blockIdx.x;
  const int bh = (bx & 7) + 8 * (bx >> 7);   // XCD-local bh grouping
  const int qcb = (bx >> 3) & 15;
  const int b = bh >> 4;
  const int nv = nvb[b];
  if (qcb * 64 >= nv) return;
  const int t = threadIdx.x;
  const int wave = t >> 6, lane = t & 63;
  const int lr = lane & 15, quad = lane >> 4;
  const int q0 = qcb * 64 + wave * 16;
  const unsigned short* qp = qcmp + ((size_t)bh << 16);
  const unsigned short* kp = kcmp + ((size_t)bh << 16);
  const unsigned short* vp = vtc + ((size_t)bh << 16);
  unsigned short* Pw = P[wave];
  bf16x8 qv0 = *(const bf16x8*)(qp + (q0 + lr) * 64 + quad * 8);
  bf16x8 qv1 = *(const bf16x8*)(qp + (q0 + lr) * 64 + 32 + quad * 8);
  float m = -INF, l = 0.f;
  f32x4 o[4] = {};
  const int sw = lr & 7;
  const int nk = (nv + 63) >> 6;
  auto stage = [&](int pp, int kc0) {
#pragma unroll
    for (int ld = 0; ld < 2; ++ld) {
      int idx = t + ld * 256;
      int row = idx >> 3;
      int g = (idx ^ row) & 7;
      ASYNC16(kp + (kc0 + row) * 64 + g * 8, &Ks[pp][idx * 8]);
    }
  };
  stage(0, 0);
  for (int it = 0; it < nk; ++it) {
    const int pp = it & 1;
    const int kc0 = it * 64;
    __syncthreads();
    if (it + 1 < nk) stage(1 - pp, kc0 + 64);
    f32x4 st[4];
    __builtin_amdgcn_s_setprio(1);
#pragma unroll
    for (int tt = 0; tt < 4; ++tt) {
      int krow = tt * 16 + lr;
      bf16x8 k0 = *(const bf16x8*)(&Ks[pp][krow * 64 + ((quad ^ sw)) * 8]);
      bf16x8 k1 = *(const bf16x8*)(&Ks[pp][krow * 64 + (((4 + quad) ^ sw)) * 8]);
      f32x4 c = {};
      c = MFMA16(k0, qv0, c);
      c = MFMA16(k1, qv1, c);
      st[tt] = c;
    }
    __builtin_amdgcn_s_setprio(0);
    // early V fragment loads (L2-resident, latency hidden under softmax VALU)
    bf16x8 vb[2][4];
#pragma unroll
    for (int sh = 0; sh < 2; ++sh)
#pragma unroll
      for (int jj = 0; jj < 4; ++jj)
        vb[sh][jj] = *(const bf16x8*)(vp + (size_t)(jj * 16 + lr) * 1024 + kc0 + (sh * 4 + quad) * 8);
    float tm = -INF;
    if (kc0 + 64 <= nv) {
      // full tile: no slot masking needed (scale already folded into Q)
#pragma unroll
      for (int tt = 0; tt < 4; ++tt)
#pragma unroll
        for (int r = 0; r < 4; ++r) tm = fmaxf(tm, st[tt][r]);
    } else {
#pragma unroll
      for (int tt = 0; tt < 4; ++tt)
#pragma unroll
        for (int r = 0; r < 4; ++r) {
          int slot = kc0 + tt * 16 + quad * 4 + r;
          float v = (slot < nv) ? st[tt][r] : -INF;
          st[tt][r] = v;
          tm = fmaxf(tm, v);
        }
    }
    tm = fmaxf(tm, __shfl_xor(tm, 16));
    tm = fmaxf(tm, __shfl_xor(tm, 32));
    float mn = fmaxf(m, tm);
    const bool resc = !__all(tm <= m + 8.f);   // defer-max: P bounded by 2^8, bf16-safe
    if (!resc) mn = m;
    float ps = 0.f;
#pragma unroll
    for (int tt = 0; tt < 4; ++tt) {
      s16x4 pv;
#pragma unroll
      for (int r = 0; r < 4; ++r) {
        float pe = EXP2(st[tt][r] - mn);
        ps += pe;
        pv[r] = (short)f2bf(pe);
      }
      *(s16x4*)(&Pw[lr * 72 + tt * 16 + quad * 4]) = pv;
    }
    ps += __shfl_xor(ps, 16);
    ps += __shfl_xor(ps, 32);
    if (resc) {
      float alpha = EXP2(m - mn);              // m==-INF (iter 0) -> alpha=0, o is 0 anyway
      l = l * alpha + ps;
      m = mn;
      float ar[4];
#pragma unroll
      for (int r = 0; r < 4; ++r) ar[r] = __shfl(alpha, quad * 4 + r);
#pragma unroll
      for (int jj = 0; jj < 4; ++jj)
#pragma unroll
        for (int r = 0; r < 4; ++r) o[jj][r] *= ar[r];
    } else {
      l += ps;
    }
    __builtin_amdgcn_s_setprio(1);
#pragma unroll
    for (int sh = 0; sh < 2; ++sh) {
      bf16x8 pa = *(const bf16x8*)(&Pw[lr * 72 + sh * 32 + quad * 8]);
#pragma unroll
      for (int jj = 0; jj < 4; ++jj)
        o[jj] = MFMA16(pa, vb[sh][jj], o[jj]);
    }
    __builtin_amdgcn_s_setprio(0);
  }
  float inv = 1.f / l;
  float ir[4];
#pragma unroll
  for (int r = 0; r < 4; ++r) ir[r] = __shfl(inv, quad * 4 + r);
  // repack o (lane holds q=quad*4+r, d=jj*16+lr) into Pw[16][72] then 16B stores
#pragma unroll
  for (int jj = 0; jj < 4; ++jj)
#pragma unroll
    for (int r = 0; r < 4; ++r)
      Pw[(quad * 4 + r) * 72 + jj * 16 + lr] = f2bf(o[jj][r] * ir[r]);
  const int h = bh & 15;
  const int slot = q0 + lr;
  if (slot < nv) {
    size_t rowb = ((size_t)(b * 1024 + slot)) * 1024 + h * 64;
#pragma unroll
    for (int p = 0; p < 2; ++p) {
      u16x8 v8 = *(const u16x8*)(&Pw[lr * 72 + (quad + p * 4) * 8]);
      *(u16x8*)(&aoc[rowb + (quad + p * 4) * 8]) = v8;
    }
  }
}

// ===== FIN: gemm_out over valid rows (masked rows pre-filled with bias by k_prep) =====
__global__ __launch_bounds__(256) void k_gemm_fin(
    const unsigned short* __restrict__ A, const unsigned short* __restrict__ Bt,
    const unsigned short* __restrict__ perm, const int* __restrict__ nvb,
    const float* __restrict__ bias, float* __restrict__ C) {
  __shared__ unsigned short SH[24576];        // 48 KB: 2 x (As[64][64] | Bs[128][64])
  const int lid = blockIdx.x;
  const int t = threadIdx.x;
  const int col = lid & 7;                    // XCD-affine col tile
  const int rt = lid >> 3;
  const int b = rt >> 4, mt = rt & 15;
  const int nv = nvb[b];
  if (mt * 64 >= nv) return;
  const int bm0 = mt * 64;
  const int bn0 = col * 128;
  const size_t abase = ((size_t)(b * 1024 + bm0)) * 1024;
  const int lane = t & 63, wave = t >> 6;
  const int wm = (wave >> 1) * 32, wn = (wave & 1) * 64;
  const int lr = lane & 15, quad = lane >> 4;
  const int sw = lr & 7;
  f32x4 acc[2][4] = {};
  auto stage = [&](int pp, int k0) {
    unsigned short* As = SH + pp * 12288;
    unsigned short* Bs = As + 4096;
#pragma unroll
    for (int j = 0; j < 2; ++j) {
      int idx = t + j * 256;
      int row = idx >> 3;
      int g = (idx ^ row) & 7;
      ASYNC16(&A[abase + (size_t)row * 1024 + k0 + g * 8], &As[idx * 8]);
    }
#pragma unroll
    for (int j = 0; j < 4; ++j) {
      int idx = t + j * 256;
      int row = idx >> 3;
      int g = (idx ^ row) & 7;
      ASYNC16(&Bt[((size_t)(bn0 + row)) * 1024 + k0 + g * 8], &Bs[idx * 8]);
    }
  };
  stage(0, 0);
  for (int it = 0; it < 16; ++it) {
    const int pp = it & 1;
    __syncthreads();
    if (it + 1 < 16) stage(1 - pp, (it + 1) * 64);
    const unsigned short* As = SH + pp * 12288;
    const unsigned short* Bs = As + 4096;
#pragma unroll
    for (int ks = 0; ks < 2; ++ks) {
      bf16x8 af[2], bfr[4];
#pragma unroll
      for (int i = 0; i < 2; ++i)
        af[i] = *(const bf16x8*)(&As[(wm + i * 16 + lr) * 64 + (((ks * 4 + quad) ^ sw)) * 8]);
#pragma unroll
      for (int j = 0; j < 4; ++j)
        bfr[j] = *(const bf16x8*)(&Bs[(wn + j * 16 + lr) * 64 + (((ks * 4 + quad) ^ sw)) * 8]);
#pragma unroll
      for (int i = 0; i < 2; ++i)
#pragma unroll
        for (int j = 0; j < 4; ++j)
          acc[i][j] = MFMA16(af[i], bfr[j], acc[i][j]);
    }
  }
  // epilogue: per-wave LDS repack (32x68 f32) -> coalesced float4 scatter stores
  __syncthreads();                            // W regions overlap staging buffers
  float* W = (float*)SH + wave * 2176;        // 32*68 floats per wave
  float bj[4];
#pragma unroll
  for (int j = 0; j < 4; ++j) bj[j] = bias[bn0 + wn + j * 16 + lr];
#pragma unroll
  for (int i = 0; i < 2; ++i)
#pragma unroll
    for (int j = 0; j < 4; ++j)
#pragma unroll
      for (int r = 0; r < 4; ++r)
        W[(i * 16 + quad * 4 + r) * 68 + j * 16 + lr] = acc[i][j][r] + bj[j];
#pragma unroll
  for (int p = 0; p < 8; ++p) {
    int fi = p * 64 + lane;
    int row = fi >> 4, c4 = fi & 15;
    int slot = bm0 + wm + row;
    if (slot < nv) {
      int tok = perm[b * 1024 + slot];
      float4 v4 = *(const float4*)(&W[row * 68 + c4 * 4]);
      *(float4*)(&C[((size_t)(b * 1024 + tok)) * 1024 + bn0 + wn + c4 * 4]) = v4;
    }
  }
}

extern "C" void kernel_launch(void* const* d_in, const int* in_sizes, int n_in,
                              void* d_out, int out_size, void* d_ws, size_t ws_size,
                              hipStream_t stream) {
  const float* x    = (const float*)d_in[0];
  const float* mask = (const float*)d_in[1];
  const float* wqkv = (const float*)d_in[2];
  const float* wout = (const float*)d_in[3];
  const float* bout = (const float*)d_in[4];
  float* out = (float*)d_out;
  char* ws = (char*)d_ws;
  // layout (40 MB + 8.2 KB):
  unsigned short* xc    = (unsigned short*)(ws);                      // [0,8)  compacted x (dead after gemm1)
  unsigned short* aoc   = (unsigned short*)(ws);                      //        alias: attn out compact
  unsigned short* wqkvt = (unsigned short*)(ws + (size_t)( 8 << 20)); // [8,14)
  unsigned short* woutt = (unsigned short*)(ws + (size_t)(14 << 20)); // [14,16)
  unsigned short* qcmp  = (unsigned short*)(ws + (size_t)(16 << 20)); // [16,24)
  unsigned short* kcmp  = (unsigned short*)(ws + (size_t)(24 << 20)); // [24,32)
  unsigned short* vt    = (unsigned short*)(ws + (size_t)(32 << 20)); // [32,40) V^T compact [bh][d][slot]
  unsigned short* perm  = (unsigned short*)(ws + (size_t)(40 << 20));           // 8 KB
  int*            nvb   = (int*)           (ws + (size_t)(40 << 20) + 8192);    // 16 B

  k_prep<<<5380, 256, 0, stream>>>(x, mask, wqkv, wout, xc, wqkvt, woutt, perm, nvb, bout, out);
  k_gemm_qkv<<<768, 256, 0, stream>>>(xc, wqkvt, nvb, qcmp, kcmp, vt);
  k_attn<<<1024, 256, 0, stream>>>(qcmp, kcmp, vt, nvb, aoc);
  k_gemm_fin<<<512, 256, 0, stream>>>(aoc, woutt, perm, nvb, bout, out);
}

// Round 7
// 142.437 us; speedup vs baseline: 1.1529x; 1.1529x over previous
//
#include <hip/hip_runtime.h>

#define INF __builtin_inff()

typedef __attribute__((ext_vector_type(8))) short bf16x8;
typedef __attribute__((ext_vector_type(4))) short s16x4;
typedef __attribute__((ext_vector_type(4))) float f32x4;
typedef __attribute__((ext_vector_type(16))) float f32x16;
typedef __attribute__((ext_vector_type(8))) unsigned short u16x8;
typedef __attribute__((ext_vector_type(4))) unsigned short u16x4;

#define MFMA16(a, b, c) __builtin_amdgcn_mfma_f32_16x16x32_bf16(a, b, c, 0, 0, 0)
#define MFMA32(a, b, c) __builtin_amdgcn_mfma_f32_32x32x16_bf16(a, b, c, 0, 0, 0)

// async global->LDS, 16B per lane; LDS dest = wave-uniform base + lane*16
#define ASYNC16(g, l) __builtin_amdgcn_global_load_lds( \
    (const __attribute__((address_space(1))) unsigned int*)(const void*)(g), \
    (__attribute__((address_space(3))) unsigned int*)(void*)(l), 16, 0, 0)

#if __has_builtin(__builtin_amdgcn_exp2f)
#define EXP2(x) __builtin_amdgcn_exp2f(x)
#else
#define EXP2(x) exp2f(x)
#endif

// 0.125 (dh^-0.5) * log2(e): folded into Q so attention runs in exp2 domain
#define QSCALE 0.18033688011112042f

__device__ __forceinline__ unsigned short f2bf(float f) {
  union { float f; unsigned u; } v; v.f = f;
  unsigned r = v.u + 0x7fffu + ((v.u >> 16) & 1u);   // RNE
  return (unsigned short)(r >> 16);
}

// == PREP: scan (4) | weight transposes (4096) | x gather-cvt (1024) | masked-row bias fill (256) ==
__global__ __launch_bounds__(256) void k_prep(
    const float* __restrict__ x, const float* __restrict__ mask,
    const float* __restrict__ wqkv, const float* __restrict__ wout,
    unsigned short* __restrict__ xc, unsigned short* __restrict__ wqkvt,
    unsigned short* __restrict__ woutt, unsigned short* __restrict__ perm,
    int* __restrict__ nvb, const float* __restrict__ bias, float* __restrict__ C) {
  __shared__ union {
    float tile[32][33];
    struct { unsigned short lperm[1024]; int wtot[4]; } sc;
  } sh;
  const int lid = blockIdx.x;
  const int t = threadIdx.x, lane = t & 63, wid = t >> 6;

  if (lid >= 5124) {
    // ---- masked-row bias fill: token masked <=> mask==0; these rows are bias-only
    const int idx = lid - 5124;
    const int b = idx >> 6, g = idx & 63;
    const float4 bv = ((const float4*)bias)[t];
    const float* mrow = mask + b * 1024 + g * 16;
#pragma unroll
    for (int j = 0; j < 16; ++j) {
      if (mrow[j] == 0.f)
        ((float4*)(C + ((size_t)(b * 1024 + g * 16 + j)) * 1024))[t] = bv;
    }
    return;
  }

  if (lid >= 4 && lid < 4100) {
    // ---- weight transpose fp32 [R][C] -> bf16 [C][R]
    int id = lid - 4;
    const float* src; unsigned short* dst; int Cc, bc, br;
    if (id < 3072) { src = wqkv; dst = wqkvt; Cc = 3072; bc = (id % 96) * 32; br = (id / 96) * 32; }
    else { id -= 3072; src = wout; dst = woutt; Cc = 1024; bc = (id & 31) * 32; br = (id >> 5) * 32; }
    const int tx = t & 31, ty = t >> 5;
#pragma unroll
    for (int i = 0; i < 32; i += 8)
      sh.tile[ty + i][tx] = src[(size_t)(br + ty + i) * Cc + bc + tx];
    __syncthreads();
#pragma unroll
    for (int i = 0; i < 32; i += 8)
      dst[(size_t)(bc + ty + i) * 1024 + br + tx] = f2bf(sh.tile[tx][ty + i]);
    return;
  }

  // ---- per-batch mask scan (both remaining roles need it)
  const int b = (lid < 4) ? lid : ((lid - 4100) >> 8);
  float4 mv = ((const float4*)(mask + b * 1024))[t];
  int v0 = mv.x != 0.f, v1 = mv.y != 0.f, v2 = mv.z != 0.f, v3 = mv.w != 0.f;
  int cnt = v0 + v1 + v2 + v3;
  int pre = cnt;
#pragma unroll
  for (int d = 1; d < 64; d <<= 1) { int n = __shfl_up(pre, d); if (lane >= d) pre += n; }
  if (lane == 63) sh.sc.wtot[wid] = pre;
  __syncthreads();
  int base = 0;
#pragma unroll
  for (int i = 0; i < 4; ++i) if (i < wid) base += sh.sc.wtot[i];
  const int nvt = sh.sc.wtot[0] + sh.sc.wtot[1] + sh.sc.wtot[2] + sh.sc.wtot[3];
  int ex = base + pre - cnt;                      // # valid before token 4t
  int vv[4] = { v0, v1, v2, v3 };

  if (lid < 4) {
    // ---- scan writeback: perm[0..nv)=valid, [nv..1024)=masked
#pragma unroll
    for (int j = 0; j < 4; ++j) {
      int tok = t * 4 + j;
      if (vv[j]) { perm[b * 1024 + ex] = (unsigned short)tok; ++ex; }
      else         perm[b * 1024 + nvt + (tok - ex)] = (unsigned short)tok;
    }
    if (t == 0) nvb[b] = nvt;
    return;
  }

  // ---- gather-convert 4 x-rows into compacted xc (zero-pad to ceil128)
#pragma unroll
  for (int j = 0; j < 4; ++j) {
    int tok = t * 4 + j;
    if (vv[j]) { sh.sc.lperm[ex] = (unsigned short)tok; ++ex; }
  }
  __syncthreads();
  const int s0 = ((lid - 4100) & 255) * 4;
  const int ce = (nvt + 127) & ~127;
#pragma unroll
  for (int j = 0; j < 4; ++j) {
    int slot = s0 + j;
    if (slot >= ce) continue;
    u16x4 o;
    if (slot < nvt) {
      int tok = sh.sc.lperm[slot];
      float4 f = ((const float4*)(x + ((size_t)(b * 1024 + tok)) * 1024))[t];
      o[0] = f2bf(f.x); o[1] = f2bf(f.y); o[2] = f2bf(f.z); o[3] = f2bf(f.w);
    } else {
      o[0] = o[1] = o[2] = o[3] = 0;
    }
    ((u16x4*)(xc + ((size_t)(b * 1024 + slot)) * 1024))[t] = o;
  }
}

// ---------- GEMM1 (double-buffered): qkv = xc @ w_qkv -> qcmp/kcmp + V^T fused ----------
// 32x32x16 MFMA (2382 vs 2075 TF ceiling; half the instruction count per K-step)
__global__ __launch_bounds__(256) void k_gemm_qkv(
    const unsigned short* __restrict__ A, const unsigned short* __restrict__ Bt,
    const int* __restrict__ nvb,
    unsigned short* __restrict__ qcmp, unsigned short* __restrict__ kcmp,
    unsigned short* __restrict__ vt) {
  __shared__ unsigned short SH[32768];        // 64 KB: 2 x (As[128][64] | Bs[128][64])
  const int lid = blockIdx.x;
  const int xcd = lid & 7, i6 = lid >> 3;
  const int colt = xcd * 3 + (i6 % 3);
  const int rowt = i6 / 3;
  const int b = rowt >> 3, mt = rowt & 7;
  const int nv = nvb[b];
  if (mt * 128 >= nv) return;
  const int bm0 = mt * 128;
  const int bn0 = colt * 128;
  const size_t abase = ((size_t)(b * 1024 + bm0)) * 1024;
  const int t = threadIdx.x;
  const int lane = t & 63, wave = t >> 6;
  const int wm = (wave >> 1) * 64, wn = (wave & 1) * 64;
  const int l31 = lane & 31, l5 = lane >> 5;
  const int sw = l31 & 7;
  f32x16 acc[2][2] = {};
  auto stage = [&](int pp, int k0) {
    unsigned short* As = SH + pp * 16384;
    unsigned short* Bs = As + 8192;
#pragma unroll
    for (int j = 0; j < 4; ++j) {
      int idx = t + j * 256;
      int row = idx >> 3;
      int g = (idx ^ row) & 7;                // chunk XOR swizzle
      ASYNC16(&A[abase + (size_t)row * 1024 + k0 + g * 8], &As[idx * 8]);
      ASYNC16(&Bt[((size_t)(bn0 + row)) * 1024 + k0 + g * 8], &Bs[idx * 8]);
    }
  };
  stage(0, 0);
  for (int it = 0; it < 16; ++it) {
    const int pp = it & 1;
    __syncthreads();
    if (it + 1 < 16) stage(1 - pp, (it + 1) * 64);
    const unsigned short* As = SH + pp * 16384;
    const unsigned short* Bs = As + 8192;
#pragma unroll
    for (int kk = 0; kk < 4; ++kk) {
      bf16x8 af[2], bfr[2];
#pragma unroll
      for (int i = 0; i < 2; ++i)
        af[i] = *(const bf16x8*)(&As[(wm + i * 32 + l31) * 64 + (((kk * 2 + l5) ^ sw)) * 8]);
#pragma unroll
      for (int j = 0; j < 2; ++j)
        bfr[j] = *(const bf16x8*)(&Bs[(wn + j * 32 + l31) * 64 + (((kk * 2 + l5) ^ sw)) * 8]);
#pragma unroll
      for (int i = 0; i < 2; ++i)
#pragma unroll
        for (int j = 0; j < 2; ++j)
          acc[i][j] = MFMA32(af[i], bfr[j], acc[i][j]);
    }
  }
  // epilogue: repack 64-row halves into SH[64][136]; Q/K row stores, V transposed stores
  // 32x32 C/D layout: col = lane&31, row = (reg&3) + 8*(reg>>2) + 4*(lane>>5)
  const int sec = bn0 >> 10;
  const int js0 = bn0 & 1023;
  const float qs = (sec == 0) ? QSCALE : 1.f;   // fold softmax scale+log2e into Q
#pragma unroll
  for (int hh = 0; hh < 2; ++hh) {
    __syncthreads();
    if ((wave >> 1) == hh) {
#pragma unroll
      for (int i = 0; i < 2; ++i)
#pragma unroll
        for (int j = 0; j < 2; ++j)
#pragma unroll
          for (int rr = 0; rr < 16; ++rr)
            SH[(i * 32 + (rr & 3) + 8 * (rr >> 2) + 4 * l5) * 136 + wn + j * 32 + l31]
              = f2bf(acc[i][j][rr] * qs);
    }
    __syncthreads();
    if (sec < 2) {
      unsigned short* dstT = sec ? kcmp : qcmp;
#pragma unroll
      for (int rr = 0; rr < 4; ++rr) {
        int lrow = (t >> 4) + rr * 16;
        int ck = t & 15;
        int slot = bm0 + hh * 64 + lrow;
        int js = js0 + ck * 8;
        int h = js >> 6, d = js & 63;
        u16x8 v = *(u16x8*)(&SH[lrow * 136 + ck * 8]);
        *(u16x8*)(&dstT[(((size_t)(b * 16 + h)) * 1024 + slot) * 64 + d]) = v;
      }
    } else {
      const int c = t & 127, seg = t >> 7;
      const int js = js0 + c, h = js >> 6, d = js & 63;
      unsigned short* vrow =
          &vt[(((size_t)(b * 16 + h)) * 64 + d) * 1024 + bm0 + hh * 64 + seg * 32];
#pragma unroll
      for (int s4 = 0; s4 < 4; ++s4) {
        u16x8 v;
#pragma unroll
        for (int s = 0; s < 8; ++s) v[s] = SH[(seg * 32 + s4 * 8 + s) * 136 + c];
        *(u16x8*)(vrow + s4 * 8) = v;
      }
    }
  }
}

// ---------- Flash attention (double-buffered K/V staging) over compacted tokens ----------
// Q pre-scaled by 0.125*log2e -> softmax in exp2 domain; defer-max rescale (THR=8)
__global__ __launch_bounds__(256, 3) void k_attn(
    const unsigned short* __restrict__ qcmp, const unsigned short* __restrict__ kcmp,
    const unsigned short* __restrict__ vtc, const int* __restrict__ nvb,
    unsigned short* __restrict__ aoc) {
  __shared__ unsigned short Ks[2][4096];
  __shared__ unsigned short Vs[2][4096];
  __shared__ unsigned short P[4][16 * 72];
  const int bx = blockIdx.x;
  const int bh = (bx & 7) + 8 * (bx >> 7);   // XCD-local bh grouping
  const int qcb = (bx >> 3) & 15;
  const int b = bh >> 4;
  const int nv = nvb[b];
  if (qcb * 64 >= nv) return;
  const int t = threadIdx.x;
  const int wave = t >> 6, lane = t & 63;
  const int lr = lane & 15, quad = lane >> 4;
  const int q0 = qcb * 64 + wave * 16;
  const unsigned short* qp = qcmp + ((size_t)bh << 16);
  const unsigned short* kp = kcmp + ((size_t)bh << 16);
  const unsigned short* vp = vtc + ((size_t)bh << 16);
  unsigned short* Pw = P[wave];
  bf16x8 qv0 = *(const bf16x8*)(qp + (q0 + lr) * 64 + quad * 8);
  bf16x8 qv1 = *(const bf16x8*)(qp + (q0 + lr) * 64 + 32 + quad * 8);
  float m = -INF, l = 0.f;
  f32x4 o[4] = {};
  const int sw = lr & 7;
  const int nk = (nv + 63) >> 6;
  auto stage = [&](int pp, int kc0) {
#pragma unroll
    for (int ld = 0; ld < 2; ++ld) {
      int idx = t + ld * 256;
      int row = idx >> 3;
      int g = (idx ^ row) & 7;
      ASYNC16(kp + (kc0 + row) * 64 + g * 8, &Ks[pp][idx * 8]);
      ASYNC16(vp + (size_t)row * 1024 + kc0 + g * 8, &Vs[pp][idx * 8]);
    }
  };
  stage(0, 0);
  for (int it = 0; it < nk; ++it) {
    const int pp = it & 1;
    const int kc0 = it * 64;
    __syncthreads();
    if (it + 1 < nk) stage(1 - pp, kc0 + 64);
    f32x4 st[4];
    __builtin_amdgcn_s_setprio(1);
#pragma unroll
    for (int tt = 0; tt < 4; ++tt) {
      int krow = tt * 16 + lr;
      bf16x8 k0 = *(const bf16x8*)(&Ks[pp][krow * 64 + ((quad ^ sw)) * 8]);
      bf16x8 k1 = *(const bf16x8*)(&Ks[pp][krow * 64 + (((4 + quad) ^ sw)) * 8]);
      f32x4 c = {};
      c = MFMA16(k0, qv0, c);
      c = MFMA16(k1, qv1, c);
      st[tt] = c;
    }
    __builtin_amdgcn_s_setprio(0);
    float tm = -INF;
    if (kc0 + 64 <= nv) {
      // full tile: no slot masking needed (scale already folded into Q)
#pragma unroll
      for (int tt = 0; tt < 4; ++tt)
#pragma unroll
        for (int r = 0; r < 4; ++r) tm = fmaxf(tm, st[tt][r]);
    } else {
#pragma unroll
      for (int tt = 0; tt < 4; ++tt)
#pragma unroll
        for (int r = 0; r < 4; ++r) {
          int slot = kc0 + tt * 16 + quad * 4 + r;
          float v = (slot < nv) ? st[tt][r] : -INF;
          st[tt][r] = v;
          tm = fmaxf(tm, v);
        }
    }
    tm = fmaxf(tm, __shfl_xor(tm, 16));
    tm = fmaxf(tm, __shfl_xor(tm, 32));
    float mn = fmaxf(m, tm);
    const bool resc = !__all(tm <= m + 8.f);   // defer-max: P bounded by 2^8, bf16-safe
    if (!resc) mn = m;
    float ps = 0.f;
#pragma unroll
    for (int tt = 0; tt < 4; ++tt) {
      s16x4 pv;
#pragma unroll
      for (int r = 0; r < 4; ++r) {
        float pe = EXP2(st[tt][r] - mn);
        ps += pe;
        pv[r] = (short)f2bf(pe);
      }
      *(s16x4*)(&Pw[lr * 72 + tt * 16 + quad * 4]) = pv;
    }
    ps += __shfl_xor(ps, 16);
    ps += __shfl_xor(ps, 32);
    if (resc) {
      float alpha = EXP2(m - mn);              // m==-INF (iter 0) -> alpha=0, o is 0 anyway
      l = l * alpha + ps;
      m = mn;
      float ar[4];
#pragma unroll
      for (int r = 0; r < 4; ++r) ar[r] = __shfl(alpha, quad * 4 + r);
#pragma unroll
      for (int jj = 0; jj < 4; ++jj)
#pragma unroll
        for (int r = 0; r < 4; ++r) o[jj][r] *= ar[r];
    } else {
      l += ps;
    }
    __builtin_amdgcn_s_setprio(1);
#pragma unroll
    for (int sh = 0; sh < 2; ++sh) {
      bf16x8 pa = *(const bf16x8*)(&Pw[lr * 72 + sh * 32 + quad * 8]);
#pragma unroll
      for (int jj = 0; jj < 4; ++jj) {
        bf16x8 vbf = *(const bf16x8*)(&Vs[pp][(jj * 16 + lr) * 64 + (((sh * 4 + quad) ^ sw)) * 8]);
        o[jj] = MFMA16(pa, vbf, o[jj]);
      }
    }
    __builtin_amdgcn_s_setprio(0);
  }
  float inv = 1.f / l;
  float ir[4];
#pragma unroll
  for (int r = 0; r < 4; ++r) ir[r] = __shfl(inv, quad * 4 + r);
  // repack o (lane holds q=quad*4+r, d=jj*16+lr) into Pw[16][72] then 16B stores
#pragma unroll
  for (int jj = 0; jj < 4; ++jj)
#pragma unroll
    for (int r = 0; r < 4; ++r)
      Pw[(quad * 4 + r) * 72 + jj * 16 + lr] = f2bf(o[jj][r] * ir[r]);
  const int h = bh & 15;
  const int slot = q0 + lr;
  if (slot < nv) {
    size_t rowb = ((size_t)(b * 1024 + slot)) * 1024 + h * 64;
#pragma unroll
    for (int p = 0; p < 2; ++p) {
      u16x8 v8 = *(const u16x8*)(&Pw[lr * 72 + (quad + p * 4) * 8]);
      *(u16x8*)(&aoc[rowb + (quad + p * 4) * 8]) = v8;
    }
  }
}

// ===== FIN: gemm_out over valid rows (masked rows pre-filled with bias by k_prep) =====
// 32x32x16 MFMA version. W repack is WAVE-LOCAL: col index excludes wn (wn applied at store).
__global__ __launch_bounds__(256) void k_gemm_fin(
    const unsigned short* __restrict__ A, const unsigned short* __restrict__ Bt,
    const unsigned short* __restrict__ perm, const int* __restrict__ nvb,
    const float* __restrict__ bias, float* __restrict__ C) {
  __shared__ unsigned short SH[24576];        // 48 KB: 2 x (As[64][64] | Bs[128][64])
  const int lid = blockIdx.x;
  const int t = threadIdx.x;
  const int col = lid & 7;                    // XCD-affine col tile
  const int rt = lid >> 3;
  const int b = rt >> 4, mt = rt & 15;
  const int nv = nvb[b];
  if (mt * 64 >= nv) return;
  const int bm0 = mt * 64;
  const int bn0 = col * 128;
  const size_t abase = ((size_t)(b * 1024 + bm0)) * 1024;
  const int lane = t & 63, wave = t >> 6;
  const int wm = (wave >> 1) * 32, wn = (wave & 1) * 64;
  const int l31 = lane & 31, l5 = lane >> 5;
  const int sw = l31 & 7;
  f32x16 acc[2] = {};
  auto stage = [&](int pp, int k0) {
    unsigned short* As = SH + pp * 12288;
    unsigned short* Bs = As + 4096;
#pragma unroll
    for (int j = 0; j < 2; ++j) {
      int idx = t + j * 256;
      int row = idx >> 3;
      int g = (idx ^ row) & 7;
      ASYNC16(&A[abase + (size_t)row * 1024 + k0 + g * 8], &As[idx * 8]);
    }
#pragma unroll
    for (int j = 0; j < 4; ++j) {
      int idx = t + j * 256;
      int row = idx >> 3;
      int g = (idx ^ row) & 7;
      ASYNC16(&Bt[((size_t)(bn0 + row)) * 1024 + k0 + g * 8], &Bs[idx * 8]);
    }
  };
  stage(0, 0);
  for (int it = 0; it < 16; ++it) {
    const int pp = it & 1;
    __syncthreads();
    if (it + 1 < 16) stage(1 - pp, (it + 1) * 64);
    const unsigned short* As = SH + pp * 12288;
    const unsigned short* Bs = As + 4096;
#pragma unroll
    for (int kk = 0; kk < 4; ++kk) {
      bf16x8 af = *(const bf16x8*)(&As[(wm + l31) * 64 + (((kk * 2 + l5) ^ sw)) * 8]);
      bf16x8 bfr[2];
#pragma unroll
      for (int j = 0; j < 2; ++j)
        bfr[j] = *(const bf16x8*)(&Bs[(wn + j * 32 + l31) * 64 + (((kk * 2 + l5) ^ sw)) * 8]);
#pragma unroll
      for (int j = 0; j < 2; ++j)
        acc[j] = MFMA32(af, bfr[j], acc[j]);
    }
  }
  // epilogue: per-wave LDS repack (32x68 f32) -> coalesced float4 scatter stores
  // 32x32 C/D layout: col = lane&31, row = (reg&3) + 8*(reg>>2) + 4*(lane>>5)
  __syncthreads();                            // W regions overlap staging buffers
  float* W = (float*)SH + wave * 2176;        // 32*68 floats per wave
  float bj[2];
#pragma unroll
  for (int j = 0; j < 2; ++j) bj[j] = bias[bn0 + wn + j * 32 + l31];
#pragma unroll
  for (int j = 0; j < 2; ++j)
#pragma unroll
    for (int rr = 0; rr < 16; ++rr)
      W[((rr & 3) + 8 * (rr >> 2) + 4 * l5) * 68 + j * 32 + l31] = acc[j][rr] + bj[j];
#pragma unroll
  for (int p = 0; p < 8; ++p) {
    int fi = p * 64 + lane;
    int row = fi >> 4, c4 = fi & 15;
    int slot = bm0 + wm + row;
    if (slot < nv) {
      int tok = perm[b * 1024 + slot];
      float4 v4 = *(const float4*)(&W[row * 68 + c4 * 4]);
      *(float4*)(&C[((size_t)(b * 1024 + tok)) * 1024 + bn0 + wn + c4 * 4]) = v4;
    }
  }
}

extern "C" void kernel_launch(void* const* d_in, const int* in_sizes, int n_in,
                              void* d_out, int out_size, void* d_ws, size_t ws_size,
                              hipStream_t stream) {
  const float* x    = (const float*)d_in[0];
  const float* mask = (const float*)d_in[1];
  const float* wqkv = (const float*)d_in[2];
  const float* wout = (const float*)d_in[3];
  const float* bout = (const float*)d_in[4];
  float* out = (float*)d_out;
  char* ws = (char*)d_ws;
  // layout (40 MB + 8.2 KB):
  unsigned short* xc    = (unsigned short*)(ws);                      // [0,8)  compacted x (dead after gemm1)
  unsigned short* aoc   = (unsigned short*)(ws);                      //        alias: attn out compact
  unsigned short* wqkvt = (unsigned short*)(ws + (size_t)( 8 << 20)); // [8,14)
  unsigned short* woutt = (unsigned short*)(ws + (size_t)(14 << 20)); // [14,16)
  unsigned short* qcmp  = (unsigned short*)(ws + (size_t)(16 << 20)); // [16,24)
  unsigned short* kcmp  = (unsigned short*)(ws + (size_t)(24 << 20)); // [24,32)
  unsigned short* vt    = (unsigned short*)(ws + (size_t)(32 << 20)); // [32,40) V^T compact [bh][d][slot]
  unsigned short* perm  = (unsigned short*)(ws + (size_t)(40 << 20));           // 8 KB
  int*            nvb   = (int*)           (ws + (size_t)(40 << 20) + 8192);    // 16 B

  k_prep<<<5380, 256, 0, stream>>>(x, mask, wqkv, wout, xc, wqkvt, woutt, perm, nvb, bout, out);
  k_gemm_qkv<<<768, 256, 0, stream>>>(xc, wqkvt, nvb, qcmp, kcmp, vt);
  k_attn<<<1024, 256, 0, stream>>>(qcmp, kcmp, vt, nvb, aoc);
  k_gemm_fin<<<512, 256, 0, stream>>>(aoc, woutt, perm, nvb, bout, out);
}

// Round 9
// 141.122 us; speedup vs baseline: 1.1636x; 1.0093x over previous
//
#include <hip/hip_runtime.h>

#define INF __builtin_inff()

typedef __attribute__((ext_vector_type(8))) short bf16x8;
typedef __attribute__((ext_vector_type(4))) short s16x4;
typedef __attribute__((ext_vector_type(4))) float f32x4;
typedef __attribute__((ext_vector_type(16))) float f32x16;
typedef __attribute__((ext_vector_type(8))) unsigned short u16x8;
typedef __attribute__((ext_vector_type(4))) unsigned short u16x4;

#define MFMA16(a, b, c) __builtin_amdgcn_mfma_f32_16x16x32_bf16(a, b, c, 0, 0, 0)
#define MFMA32(a, b, c) __builtin_amdgcn_mfma_f32_32x32x16_bf16(a, b, c, 0, 0, 0)

// async global->LDS, 16B per lane; LDS dest = wave-uniform base + lane*16
#define ASYNC16(g, l) __builtin_amdgcn_global_load_lds( \
    (const __attribute__((address_space(1))) unsigned int*)(const void*)(g), \
    (__attribute__((address_space(3))) unsigned int*)(void*)(l), 16, 0, 0)

#if __has_builtin(__builtin_amdgcn_exp2f)
#define EXP2(x) __builtin_amdgcn_exp2f(x)
#else
#define EXP2(x) exp2f(x)
#endif

// 0.125 (dh^-0.5) * log2(e): folded into Q so attention runs in exp2 domain
#define QSCALE 0.18033688011112042f

__device__ __forceinline__ unsigned short f2bf(float f) {
  union { float f; unsigned u; } v; v.f = f;
  unsigned r = v.u + 0x7fffu + ((v.u >> 16) & 1u);   // RNE
  return (unsigned short)(r >> 16);
}

// == PREP: scan (4) | weight transposes (4096) | x gather-cvt (1024) | masked-row bias fill (256) ==
__global__ __launch_bounds__(256) void k_prep(
    const float* __restrict__ x, const float* __restrict__ mask,
    const float* __restrict__ wqkv, const float* __restrict__ wout,
    unsigned short* __restrict__ xc, unsigned short* __restrict__ wqkvt,
    unsigned short* __restrict__ woutt, unsigned short* __restrict__ perm,
    int* __restrict__ nvb, const float* __restrict__ bias, float* __restrict__ C) {
  __shared__ union {
    float tile[32][33];
    struct { unsigned short lperm[1024]; int wtot[4]; } sc;
  } sh;
  const int lid = blockIdx.x;
  const int t = threadIdx.x, lane = t & 63, wid = t >> 6;

  if (lid >= 5124) {
    // ---- masked-row bias fill: token masked <=> mask==0; these rows are bias-only
    const int idx = lid - 5124;
    const int b = idx >> 6, g = idx & 63;
    const float4 bv = ((const float4*)bias)[t];
    const float* mrow = mask + b * 1024 + g * 16;
#pragma unroll
    for (int j = 0; j < 16; ++j) {
      if (mrow[j] == 0.f)
        ((float4*)(C + ((size_t)(b * 1024 + g * 16 + j)) * 1024))[t] = bv;
    }
    return;
  }

  if (lid >= 4 && lid < 4100) {
    // ---- weight transpose fp32 [R][C] -> bf16 [C][R]
    int id = lid - 4;
    const float* src; unsigned short* dst; int Cc, bc, br;
    if (id < 3072) { src = wqkv; dst = wqkvt; Cc = 3072; bc = (id % 96) * 32; br = (id / 96) * 32; }
    else { id -= 3072; src = wout; dst = woutt; Cc = 1024; bc = (id & 31) * 32; br = (id >> 5) * 32; }
    const int tx = t & 31, ty = t >> 5;
#pragma unroll
    for (int i = 0; i < 32; i += 8)
      sh.tile[ty + i][tx] = src[(size_t)(br + ty + i) * Cc + bc + tx];
    __syncthreads();
#pragma unroll
    for (int i = 0; i < 32; i += 8)
      dst[(size_t)(bc + ty + i) * 1024 + br + tx] = f2bf(sh.tile[tx][ty + i]);
    return;
  }

  // ---- per-batch mask scan (both remaining roles need it)
  const int b = (lid < 4) ? lid : ((lid - 4100) >> 8);
  float4 mv = ((const float4*)(mask + b * 1024))[t];
  int v0 = mv.x != 0.f, v1 = mv.y != 0.f, v2 = mv.z != 0.f, v3 = mv.w != 0.f;
  int cnt = v0 + v1 + v2 + v3;
  int pre = cnt;
#pragma unroll
  for (int d = 1; d < 64; d <<= 1) { int n = __shfl_up(pre, d); if (lane >= d) pre += n; }
  if (lane == 63) sh.sc.wtot[wid] = pre;
  __syncthreads();
  int base = 0;
#pragma unroll
  for (int i = 0; i < 4; ++i) if (i < wid) base += sh.sc.wtot[i];
  const int nvt = sh.sc.wtot[0] + sh.sc.wtot[1] + sh.sc.wtot[2] + sh.sc.wtot[3];
  int ex = base + pre - cnt;                      // # valid before token 4t
  int vv[4] = { v0, v1, v2, v3 };

  if (lid < 4) {
    // ---- scan writeback: perm[0..nv)=valid, [nv..1024)=masked
#pragma unroll
    for (int j = 0; j < 4; ++j) {
      int tok = t * 4 + j;
      if (vv[j]) { perm[b * 1024 + ex] = (unsigned short)tok; ++ex; }
      else         perm[b * 1024 + nvt + (tok - ex)] = (unsigned short)tok;
    }
    if (t == 0) nvb[b] = nvt;
    return;
  }

  // ---- gather-convert 4 x-rows into compacted xc (zero-pad to ceil128)
#pragma unroll
  for (int j = 0; j < 4; ++j) {
    int tok = t * 4 + j;
    if (vv[j]) { sh.sc.lperm[ex] = (unsigned short)tok; ++ex; }
  }
  __syncthreads();
  const int s0 = ((lid - 4100) & 255) * 4;
  const int ce = (nvt + 127) & ~127;
#pragma unroll
  for (int j = 0; j < 4; ++j) {
    int slot = s0 + j;
    if (slot >= ce) continue;
    u16x4 o;
    if (slot < nvt) {
      int tok = sh.sc.lperm[slot];
      float4 f = ((const float4*)(x + ((size_t)(b * 1024 + tok)) * 1024))[t];
      o[0] = f2bf(f.x); o[1] = f2bf(f.y); o[2] = f2bf(f.z); o[3] = f2bf(f.w);
    } else {
      o[0] = o[1] = o[2] = o[3] = 0;
    }
    ((u16x4*)(xc + ((size_t)(b * 1024 + slot)) * 1024))[t] = o;
  }
}

// ---------- GEMM1 (double-buffered): qkv = xc @ w_qkv -> qcmp/kcmp + V^T fused ----------
// 32x32x16 MFMA (2382 vs 2075 TF ceiling; half the instruction count per K-step)
__global__ __launch_bounds__(256) void k_gemm_qkv(
    const unsigned short* __restrict__ A, const unsigned short* __restrict__ Bt,
    const int* __restrict__ nvb,
    unsigned short* __restrict__ qcmp, unsigned short* __restrict__ kcmp,
    unsigned short* __restrict__ vt) {
  __shared__ unsigned short SH[32768];        // 64 KB: 2 x (As[128][64] | Bs[128][64])
  const int lid = blockIdx.x;
  const int xcd = lid & 7, i6 = lid >> 3;
  const int colt = xcd * 3 + (i6 % 3);
  const int rowt = i6 / 3;
  const int b = rowt >> 3, mt = rowt & 7;
  const int nv = nvb[b];
  if (mt * 128 >= nv) return;
  const int bm0 = mt * 128;
  const int bn0 = colt * 128;
  const size_t abase = ((size_t)(b * 1024 + bm0)) * 1024;
  const int t = threadIdx.x;
  const int lane = t & 63, wave = t >> 6;
  const int wm = (wave >> 1) * 64, wn = (wave & 1) * 64;
  const int l31 = lane & 31, l5 = lane >> 5;
  const int sw = l31 & 7;
  f32x16 acc[2][2] = {};
  auto stage = [&](int pp, int k0) {
    unsigned short* As = SH + pp * 16384;
    unsigned short* Bs = As + 8192;
#pragma unroll
    for (int j = 0; j < 4; ++j) {
      int idx = t + j * 256;
      int row = idx >> 3;
      int g = (idx ^ row) & 7;                // chunk XOR swizzle
      ASYNC16(&A[abase + (size_t)row * 1024 + k0 + g * 8], &As[idx * 8]);
      ASYNC16(&Bt[((size_t)(bn0 + row)) * 1024 + k0 + g * 8], &Bs[idx * 8]);
    }
  };
  stage(0, 0);
  for (int it = 0; it < 16; ++it) {
    const int pp = it & 1;
    __syncthreads();
    if (it + 1 < 16) stage(1 - pp, (it + 1) * 64);
    const unsigned short* As = SH + pp * 16384;
    const unsigned short* Bs = As + 8192;
#pragma unroll
    for (int kk = 0; kk < 4; ++kk) {
      bf16x8 af[2], bfr[2];
#pragma unroll
      for (int i = 0; i < 2; ++i)
        af[i] = *(const bf16x8*)(&As[(wm + i * 32 + l31) * 64 + (((kk * 2 + l5) ^ sw)) * 8]);
#pragma unroll
      for (int j = 0; j < 2; ++j)
        bfr[j] = *(const bf16x8*)(&Bs[(wn + j * 32 + l31) * 64 + (((kk * 2 + l5) ^ sw)) * 8]);
#pragma unroll
      for (int i = 0; i < 2; ++i)
#pragma unroll
        for (int j = 0; j < 2; ++j)
          acc[i][j] = MFMA32(af[i], bfr[j], acc[i][j]);
    }
  }
  // epilogue: repack 64-row halves into SH[64][136]; Q/K row stores, V transposed stores
  // 32x32 C/D layout: col = lane&31, row = (reg&3) + 8*(reg>>2) + 4*(lane>>5)
  const int sec = bn0 >> 10;
  const int js0 = bn0 & 1023;
  const float qs = (sec == 0) ? QSCALE : 1.f;   // fold softmax scale+log2e into Q
#pragma unroll
  for (int hh = 0; hh < 2; ++hh) {
    __syncthreads();
    if ((wave >> 1) == hh) {
#pragma unroll
      for (int i = 0; i < 2; ++i)
#pragma unroll
        for (int j = 0; j < 2; ++j)
#pragma unroll
          for (int rr = 0; rr < 16; ++rr)
            SH[(i * 32 + (rr & 3) + 8 * (rr >> 2) + 4 * l5) * 136 + wn + j * 32 + l31]
              = f2bf(acc[i][j][rr] * qs);
    }
    __syncthreads();
    if (sec < 2) {
      unsigned short* dstT = sec ? kcmp : qcmp;
#pragma unroll
      for (int rr = 0; rr < 4; ++rr) {
        int lrow = (t >> 4) + rr * 16;
        int ck = t & 15;
        int slot = bm0 + hh * 64 + lrow;
        int js = js0 + ck * 8;
        int h = js >> 6, d = js & 63;
        u16x8 v = *(u16x8*)(&SH[lrow * 136 + ck * 8]);
        *(u16x8*)(&dstT[(((size_t)(b * 16 + h)) * 1024 + slot) * 64 + d]) = v;
      }
    } else {
      const int c = t & 127, seg = t >> 7;
      const int js = js0 + c, h = js >> 6, d = js & 63;
      unsigned short* vrow =
          &vt[(((size_t)(b * 16 + h)) * 64 + d) * 1024 + bm0 + hh * 64 + seg * 32];
#pragma unroll
      for (int s4 = 0; s4 < 4; ++s4) {
        u16x8 v;
#pragma unroll
        for (int s = 0; s < 8; ++s) v[s] = SH[(seg * 32 + s4 * 8 + s) * 136 + c];
        *(u16x8*)(vrow + s4 * 8) = v;
      }
    }
  }
}

// ---------- Flash attention (double-buffered K/V staging) over compacted tokens ----------
// Q pre-scaled by 0.125*log2e -> softmax in exp2 domain; defer-max rescale (THR=8)
__global__ __launch_bounds__(256, 3) void k_attn(
    const unsigned short* __restrict__ qcmp, const unsigned short* __restrict__ kcmp,
    const unsigned short* __restrict__ vtc, const int* __restrict__ nvb,
    unsigned short* __restrict__ aoc) {
  __shared__ unsigned short Ks[2][4096];
  __shared__ unsigned short Vs[2][4096];
  __shared__ unsigned short P[4][16 * 72];
  const int bx = blockIdx.x;
  const int bh = (bx & 7) + 8 * (bx >> 7);   // XCD-local bh grouping
  const int qcb = (bx >> 3) & 15;
  const int b = bh >> 4;
  const int nv = nvb[b];
  if (qcb * 64 >= nv) return;
  const int t = threadIdx.x;
  const int wave = t >> 6, lane = t & 63;
  const int lr = lane & 15, quad = lane >> 4;
  const int q0 = qcb * 64 + wave * 16;
  const unsigned short* qp = qcmp + ((size_t)bh << 16);
  const unsigned short* kp = kcmp + ((size_t)bh << 16);
  const unsigned short* vp = vtc + ((size_t)bh << 16);
  unsigned short* Pw = P[wave];
  bf16x8 qv0 = *(const bf16x8*)(qp + (q0 + lr) * 64 + quad * 8);
  bf16x8 qv1 = *(const bf16x8*)(qp + (q0 + lr) * 64 + 32 + quad * 8);
  float m = -INF, l = 0.f;
  f32x4 o[4] = {};
  const int sw = lr & 7;
  const int nk = (nv + 63) >> 6;
  auto stage = [&](int pp, int kc0) {
#pragma unroll
    for (int ld = 0; ld < 2; ++ld) {
      int idx = t + ld * 256;
      int row = idx >> 3;
      int g = (idx ^ row) & 7;
      ASYNC16(kp + (kc0 + row) * 64 + g * 8, &Ks[pp][idx * 8]);
      ASYNC16(vp + (size_t)row * 1024 + kc0 + g * 8, &Vs[pp][idx * 8]);
    }
  };
  stage(0, 0);
  for (int it = 0; it < nk; ++it) {
    const int pp = it & 1;
    const int kc0 = it * 64;
    __syncthreads();
    if (it + 1 < nk) stage(1 - pp, kc0 + 64);
    f32x4 st[4];
    __builtin_amdgcn_s_setprio(1);
#pragma unroll
    for (int tt = 0; tt < 4; ++tt) {
      int krow = tt * 16 + lr;
      bf16x8 k0 = *(const bf16x8*)(&Ks[pp][krow * 64 + ((quad ^ sw)) * 8]);
      bf16x8 k1 = *(const bf16x8*)(&Ks[pp][krow * 64 + (((4 + quad) ^ sw)) * 8]);
      f32x4 c = {};
      c = MFMA16(k0, qv0, c);
      c = MFMA16(k1, qv1, c);
      st[tt] = c;
    }
    __builtin_amdgcn_s_setprio(0);
    float tm = -INF;
    if (kc0 + 64 <= nv) {
      // full tile: no slot masking needed (scale already folded into Q)
#pragma unroll
      for (int tt = 0; tt < 4; ++tt)
#pragma unroll
        for (int r = 0; r < 4; ++r) tm = fmaxf(tm, st[tt][r]);
    } else {
#pragma unroll
      for (int tt = 0; tt < 4; ++tt)
#pragma unroll
        for (int r = 0; r < 4; ++r) {
          int slot = kc0 + tt * 16 + quad * 4 + r;
          float v = (slot < nv) ? st[tt][r] : -INF;
          st[tt][r] = v;
          tm = fmaxf(tm, v);
        }
    }
    tm = fmaxf(tm, __shfl_xor(tm, 16));
    tm = fmaxf(tm, __shfl_xor(tm, 32));
    float mn = fmaxf(m, tm);
    const bool resc = !__all(tm <= m + 8.f);   // defer-max: P bounded by 2^8, bf16-safe
    if (!resc) mn = m;
    float ps = 0.f;
#pragma unroll
    for (int tt = 0; tt < 4; ++tt) {
      s16x4 pv;
#pragma unroll
      for (int r = 0; r < 4; ++r) {
        float pe = EXP2(st[tt][r] - mn);
        ps += pe;
        pv[r] = (short)f2bf(pe);
      }
      *(s16x4*)(&Pw[lr * 72 + tt * 16 + quad * 4]) = pv;
    }
    ps += __shfl_xor(ps, 16);
    ps += __shfl_xor(ps, 32);
    if (resc) {
      float alpha = EXP2(m - mn);              // m==-INF (iter 0) -> alpha=0, o is 0 anyway
      l = l * alpha + ps;
      m = mn;
      float ar[4];
#pragma unroll
      for (int r = 0; r < 4; ++r) ar[r] = __shfl(alpha, quad * 4 + r);
#pragma unroll
      for (int jj = 0; jj < 4; ++jj)
#pragma unroll
        for (int r = 0; r < 4; ++r) o[jj][r] *= ar[r];
    } else {
      l += ps;
    }
    __builtin_amdgcn_s_setprio(1);
#pragma unroll
    for (int sh = 0; sh < 2; ++sh) {
      bf16x8 pa = *(const bf16x8*)(&Pw[lr * 72 + sh * 32 + quad * 8]);
#pragma unroll
      for (int jj = 0; jj < 4; ++jj) {
        bf16x8 vbf = *(const bf16x8*)(&Vs[pp][(jj * 16 + lr) * 64 + (((sh * 4 + quad) ^ sw)) * 8]);
        o[jj] = MFMA16(pa, vbf, o[jj]);
      }
    }
    __builtin_amdgcn_s_setprio(0);
  }
  float inv = 1.f / l;
  float ir[4];
#pragma unroll
  for (int r = 0; r < 4; ++r) ir[r] = __shfl(inv, quad * 4 + r);
  // repack o (lane holds q=quad*4+r, d=jj*16+lr) into Pw[16][72] then 16B stores
#pragma unroll
  for (int jj = 0; jj < 4; ++jj)
#pragma unroll
    for (int r = 0; r < 4; ++r)
      Pw[(quad * 4 + r) * 72 + jj * 16 + lr] = f2bf(o[jj][r] * ir[r]);
  const int h = bh & 15;
  const int slot = q0 + lr;
  if (slot < nv) {
    size_t rowb = ((size_t)(b * 1024 + slot)) * 1024 + h * 64;
#pragma unroll
    for (int p = 0; p < 2; ++p) {
      u16x8 v8 = *(const u16x8*)(&Pw[lr * 72 + (quad + p * 4) * 8]);
      *(u16x8*)(&aoc[rowb + (quad + p * 4) * 8]) = v8;
    }
  }
}

// ===== FIN: gemm_out over valid rows (masked rows pre-filled with bias by k_prep) =====
// 32x32x16 MFMA version. W repack is WAVE-LOCAL: col index excludes wn (wn applied at store).
__global__ __launch_bounds__(256) void k_gemm_fin(
    const unsigned short* __restrict__ A, const unsigned short* __restrict__ Bt,
    const unsigned short* __restrict__ perm, const int* __restrict__ nvb,
    const float* __restrict__ bias, float* __restrict__ C) {
  __shared__ unsigned short SH[24576];        // 48 KB: 2 x (As[64][64] | Bs[128][64])
  const int lid = blockIdx.x;
  const int t = threadIdx.x;
  const int col = lid & 7;                    // XCD-affine col tile
  const int rt = lid >> 3;
  const int b = rt >> 4, mt = rt & 15;
  const int nv = nvb[b];
  if (mt * 64 >= nv) return;
  const int bm0 = mt * 64;
  const int bn0 = col * 128;
  const size_t abase = ((size_t)(b * 1024 + bm0)) * 1024;
  const int lane = t & 63, wave = t >> 6;
  const int wm = (wave >> 1) * 32, wn = (wave & 1) * 64;
  const int l31 = lane & 31, l5 = lane >> 5;
  const int sw = l31 & 7;
  f32x16 acc[2] = {};
  auto stage = [&](int pp, int k0) {
    unsigned short* As = SH + pp * 12288;
    unsigned short* Bs = As + 4096;
#pragma unroll
    for (int j = 0; j < 2; ++j) {
      int idx = t + j * 256;
      int row = idx >> 3;
      int g = (idx ^ row) & 7;
      ASYNC16(&A[abase + (size_t)row * 1024 + k0 + g * 8], &As[idx * 8]);
    }
#pragma unroll
    for (int j = 0; j < 4; ++j) {
      int idx = t + j * 256;
      int row = idx >> 3;
      int g = (idx ^ row) & 7;
      ASYNC16(&Bt[((size_t)(bn0 + row)) * 1024 + k0 + g * 8], &Bs[idx * 8]);
    }
  };
  stage(0, 0);
  for (int it = 0; it < 16; ++it) {
    const int pp = it & 1;
    __syncthreads();
    if (it + 1 < 16) stage(1 - pp, (it + 1) * 64);
    const unsigned short* As = SH + pp * 12288;
    const unsigned short* Bs = As + 4096;
#pragma unroll
    for (int kk = 0; kk < 4; ++kk) {
      bf16x8 af = *(const bf16x8*)(&As[(wm + l31) * 64 + (((kk * 2 + l5) ^ sw)) * 8]);
      bf16x8 bfr[2];
#pragma unroll
      for (int j = 0; j < 2; ++j)
        bfr[j] = *(const bf16x8*)(&Bs[(wn + j * 32 + l31) * 64 + (((kk * 2 + l5) ^ sw)) * 8]);
#pragma unroll
      for (int j = 0; j < 2; ++j)
        acc[j] = MFMA32(af, bfr[j], acc[j]);
    }
  }
  // epilogue: per-wave LDS repack (32x68 f32) -> coalesced float4 scatter stores
  // 32x32 C/D layout: col = lane&31, row = (reg&3) + 8*(reg>>2) + 4*(lane>>5)
  __syncthreads();                            // W regions overlap staging buffers
  float* W = (float*)SH + wave * 2176;        // 32*68 floats per wave
  float bj[2];
#pragma unroll
  for (int j = 0; j < 2; ++j) bj[j] = bias[bn0 + wn + j * 32 + l31];
#pragma unroll
  for (int j = 0; j < 2; ++j)
#pragma unroll
    for (int rr = 0; rr < 16; ++rr)
      W[((rr & 3) + 8 * (rr >> 2) + 4 * l5) * 68 + j * 32 + l31] = acc[j][rr] + bj[j];
#pragma unroll
  for (int p = 0; p < 8; ++p) {
    int fi = p * 64 + lane;
    int row = fi >> 4, c4 = fi & 15;
    int slot = bm0 + wm + row;
    if (slot < nv) {
      int tok = perm[b * 1024 + slot];
      float4 v4 = *(const float4*)(&W[row * 68 + c4 * 4]);
      *(float4*)(&C[((size_t)(b * 1024 + tok)) * 1024 + bn0 + wn + c4 * 4]) = v4;
    }
  }
}

extern "C" void kernel_launch(void* const* d_in, const int* in_sizes, int n_in,
                              void* d_out, int out_size, void* d_ws, size_t ws_size,
                              hipStream_t stream) {
  const float* x    = (const float*)d_in[0];
  const float* mask = (const float*)d_in[1];
  const float* wqkv = (const float*)d_in[2];
  const float* wout = (const float*)d_in[3];
  const float* bout = (const float*)d_in[4];
  float* out = (float*)d_out;
  char* ws = (char*)d_ws;
  // layout (40 MB + 8.2 KB):
  unsigned short* xc    = (unsigned short*)(ws);                      // [0,8)  compacted x (dead after gemm1)
  unsigned short* aoc   = (unsigned short*)(ws);                      //        alias: attn out compact
  unsigned short* wqkvt = (unsigned short*)(ws + (size_t)( 8 << 20)); // [8,14)
  unsigned short* woutt = (unsigned short*)(ws + (size_t)(14 << 20)); // [14,16)
  unsigned short* qcmp  = (unsigned short*)(ws + (size_t)(16 << 20)); // [16,24)
  unsigned short* kcmp  = (unsigned short*)(ws + (size_t)(24 << 20)); // [24,32)
  unsigned short* vt    = (unsigned short*)(ws + (size_t)(32 << 20)); // [32,40) V^T compact [bh][d][slot]
  unsigned short* perm  = (unsigned short*)(ws + (size_t)(40 << 20));           // 8 KB
  int*            nvb   = (int*)           (ws + (size_t)(40 << 20) + 8192);    // 16 B

  k_prep<<<5380, 256, 0, stream>>>(x, mask, wqkv, wout, xc, wqkvt, woutt, perm, nvb, bout, out);
  k_gemm_qkv<<<768, 256, 0, stream>>>(xc, wqkvt, nvb, qcmp, kcmp, vt);
  k_attn<<<1024, 256, 0, stream>>>(qcmp, kcmp, vt, nvb, aoc);
  k_gemm_fin<<<512, 256, 0, stream>>>(aoc, woutt, perm, nvb, bout, out);
}